// Round 24
// baseline (82.983 us; speedup 1.0000x reference)
//
#include <hip/hip_runtime.h>
#include <math.h>

#define SEQLEN   2048
#define HIDDEN   1024
#define NMODES   32
#define CHANNELS 4096
#define CHB      16      // channels per block
#define TPG      1024    // timesteps per chunk-group (16 chunks x 64)
#define XP       72      // xbuf inner stride (bf16), 144B rows: 16B-aligned
#define CSTR     1032    // ubuf channel stride in shorts (+16B de-conflict)

typedef float  f2    __attribute__((ext_vector_type(2)));
typedef short  s8v   __attribute__((ext_vector_type(8)));
typedef float  f32x4 __attribute__((ext_vector_type(4)));
union Frag { s8v s; unsigned u[4]; };

// ---- ws layout (bytes) ---------------------------------------------------
#define SZ_V  (1024*64*64*2)              // V table bf16, 8 MiB
#define SZ_M  (1024*64*64*2)              // M table bf16, 8 MiB
#define SZ_K  (1024*64*4)                 // kc f32, 256 KiB
#define SZ_Q  (1024*64*4)                 // A^64 f32, 256 KiB
#define OFF_M (SZ_V)
#define OFF_K (OFF_M + SZ_M)
#define OFF_Q (OFF_K + SZ_K)
#define OFF_C (OFF_Q + SZ_Q)              // carry f32 [ch][64], 1 MiB
#define SZ_C  (CHANNELS*64*4)
#define OFF_F (OFF_C + SZ_C)              // flags int[256]

// ---- helpers -------------------------------------------------------------
template <int CTRL>
__device__ __forceinline__ float dpp_add(float p) {
    int t = __builtin_amdgcn_update_dpp(0, __float_as_int(p), CTRL, 0xF, 0xF, true);
    return p + __int_as_float(t);
}
template <int CTRL>
__device__ __forceinline__ float dpp_shr(float x) {   // lane i <- lane i-s (0 fill)
    int t = __builtin_amdgcn_update_dpp(0, __float_as_int(x), CTRL, 0xF, 0xF, true);
    return __int_as_float(t);
}
__device__ __forceinline__ float sum32_to16(float p) {
    p = dpp_add<0xB1>(p); p = dpp_add<0x4E>(p);
    p = dpp_add<0x124>(p); p = dpp_add<0x128>(p);
    p = dpp_add<0x142>(p);
    return p;
}
__device__ __forceinline__ unsigned cvt_pk_bf16(float lo, float hi) {
    unsigned d; asm("v_cvt_pk_bf16_f32 %0, %1, %2" : "=v"(d) : "v"(lo), "v"(hi)); return d;
}
__device__ __forceinline__ unsigned short bf16of(float x) {
    return (unsigned short)(cvt_pk_bf16(x, x) & 0xffffu);
}
__device__ __forceinline__ float bf2f(unsigned s) {
    return __uint_as_float(s << 16);
}

__device__ __forceinline__ void coef1(
    const float* __restrict__ log_dt, const float* __restrict__ A_log,
    const float* __restrict__ A_imag, const float* __restrict__ Bp,
    const float* __restrict__ Cp, int h, int m,
    float& adr, float& adi, float& bpr, float& bpi)
{
    const int idx = h * NMODES + m;
    const float dt = expf(log_dt[h]);
    const float hd = 0.5f * dt;
    const float ar = -expf(A_log[idx]);
    const float ai = A_imag[idx];
    const float dr = 1.f - hd * ar, di = -hd * ai;
    const float inv = 1.f / (dr * dr + di * di);
    const float nr = 1.f + hd * ar, ni = hd * ai;
    adr = (nr * dr + ni * di) * inv;
    adi = (ni * dr - nr * di) * inv;
    const float tbr = dt * Bp[idx * 2], tbi = dt * Bp[idx * 2 + 1];
    const float bdr = (tbr * dr + tbi * di) * inv;
    const float bdi = (tbi * dr - tbr * di) * inv;
    const float cr = 2.f * Cp[idx * 2], ci = 2.f * Cp[idx * 2 + 1];
    bpr = cr * bdr - ci * bdi;
    bpi = cr * bdi + ci * bdr;
}

// ---- Kernel 0: per-h tables + kc + Qt (A^64) — R23 verbatim --------------
__global__ __launch_bounds__(256) void ssm_tables(
    const float* __restrict__ log_dt, const float* __restrict__ Dp,
    const float* __restrict__ A_log, const float* __restrict__ A_imag,
    const float* __restrict__ Bp, const float* __restrict__ Cp,
    unsigned short* __restrict__ Vt, unsigned short* __restrict__ Mt,
    float* __restrict__ kct, float* __restrict__ Qt)
{
    const int h = blockIdx.x >> 3, dg = blockIdx.x & 7;
    const int tid = threadIdx.x, wv = tid >> 6, l = tid & 63;
    const int m = l & 31;
    const int d = (dg * 4 + wv) * 2 + (l >> 5);

    float adr, adi, bpr, bpi;
    coef1(log_dt, A_log, A_imag, Bp, Cp, h, m, adr, adi, bpr, bpi);

    float Pr = 1.f, Pi = 0.f, Qr = adr, Qi = adi;
    #pragma unroll
    for (int bit = 0; bit < 6; ++bit) {
        if ((d >> bit) & 1) { float t = Pr*Qr - Pi*Qi; Pi = Pr*Qi + Pi*Qr; Pr = t; }
        float tq = Qr*Qr - Qi*Qi; Qi = 2.f*Qr*Qi; Qr = tq;
    }
    const float wr  = Pr*bpr - Pi*bpi, wi  = Pr*bpi + Pi*bpr;   // A^d B'
    const float apr = Pr*adr - Pi*adi, api = Pr*adi + Pi*adr;   // A^{d+1}

    const size_t hb = (size_t)h * 64;
    Vt[(hb + m)      * 64 + (63 - d)] = bf16of(wr);
    Vt[(hb + 32 + m) * 64 + (63 - d)] = bf16of(wi);
    Mt[(hb + d) * 64 + m]       = bf16of(apr);
    Mt[(hb + d) * 64 + 32 + m]  = bf16of(-api);
    if (d == 63) {                       // A^64 (exact f32) for the prefix
        Qt[hb + m]      = apr;
        Qt[hb + 32 + m] = api;
    }

    float s = sum32_to16(wr);
    if ((l & 31) == 16) kct[hb + d] = s + (d == 0 ? Dp[h] : 0.f);
}

// ---- staging: u tile (1024 t x 16 ch) -> frag-ordered bf16 LDS -----------
__device__ __forceinline__ void stage_frag_u(
    const float* __restrict__ ug, unsigned short* __restrict__ ubuf, int tid)
{
    #pragma unroll
    for (int it = 0; it < 16; ++it) {
        const int t_l = it * 64 + (tid >> 2);
        const int c4  = (tid & 3) * 4;
        const float4 g = *(const float4*)(ug + (size_t)t_l * HIDDEN + c4);
        const int n = t_l >> 6, rr = t_l & 63, ksw = rr >> 5, r5 = rr & 31;
        const int lane = (r5 >> 3) * 16 + n, j = r5 & 7;
        const int base = (ksw * 64 + lane) * 8 + j;
        ubuf[(c4 + 0) * CSTR + base] = bf16of(g.x);
        ubuf[(c4 + 1) * CSTR + base] = bf16of(g.y);
        ubuf[(c4 + 2) * CSTR + base] = bf16of(g.z);
        ubuf[(c4 + 3) * CSTR + base] = bf16of(g.w);
    }
    __syncthreads();
}

// ---- Fused: states -> prefix(noC) -> T x U -> [cg1: wait+correct] -> M x X
// grid = 512: blockIdx 0..255 = cg0, 256..511 = cg1. LDS ~80.9KB, 2 blk/CU.
__global__ __launch_bounds__(256) void ssm_fused(
    const float* __restrict__ input,
    const unsigned short* __restrict__ Vt, const unsigned short* __restrict__ Mt,
    const float* __restrict__ kct, const float* __restrict__ Qt,
    float* __restrict__ carry, int* __restrict__ flags, float* __restrict__ out)
{
    __shared__ __align__(16) unsigned short ubuf[CHB * CSTR];   // u frags; later y tile
    __shared__ float kcP[CHB][128];
    __shared__ __align__(16) unsigned short xbuf[CHB][17][XP];  // abs states bf16

    const int tid = threadIdx.x, wv = tid >> 6, l = tid & 63;
    const int cgp = blockIdx.x >> 8;
    const int chb = blockIdx.x & 255;
    const int chbase = chb * CHB;
    const int b = chbase >> 10, h0 = chbase & (HIDDEN - 1);
    const int lr = l & 15, lk8 = ((l >> 4) & 3) * 8, lo = (l >> 4) * 4;

    #pragma unroll
    for (int q = 0; q < 8; ++q) {
        const int idx = q * 256 + tid, chl = idx >> 7, k = idx & 127;
        kcP[chl][k] = (k < 64) ? kct[(size_t)(h0 + chl) * 64 + (63 - k)] : 0.f;
    }
    stage_frag_u(input + ((size_t)b * SEQLEN + cgp * TPG) * HIDDEN + h0, ubuf, tid);

    // ---- phase 1: V x U -> local chunk-end states ----
    f32x4 acc_s[4][4];
    #pragma unroll
    for (int c = 0; c < 4; ++c) {
        const int chl = wv * 4 + c, h = h0 + chl;
        Frag UB0, UB1;
        UB0.s = *(const s8v*)(ubuf + chl * CSTR + l * 8);
        UB1.s = *(const s8v*)(ubuf + chl * CSTR + (64 + l) * 8);
        #pragma unroll
        for (int mt = 0; mt < 4; ++mt) { f32x4 z = {0.f,0.f,0.f,0.f}; acc_s[c][mt] = z; }
        const unsigned short* Vh = Vt + (size_t)h * 4096;
        #pragma unroll
        for (int mt = 0; mt < 4; ++mt) {
            Frag VA0, VA1;
            VA0.s = *(const s8v*)(Vh + (16 * mt + lr) * 64 + lk8);
            VA1.s = *(const s8v*)(Vh + (16 * mt + lr) * 64 + 32 + lk8);
            acc_s[c][mt] = __builtin_amdgcn_mfma_f32_16x16x32_bf16(VA0.s, UB0.s, acc_s[c][mt], 0, 0, 0);
            acc_s[c][mt] = __builtin_amdgcn_mfma_f32_16x16x32_bf16(VA1.s, UB1.s, acc_s[c][mt], 0, 0, 0);
        }
    }

    // ---- prefix WITHOUT carry (both groups; no wait) ----
    #pragma unroll
    for (int c = 0; c < 4; ++c) {
        const int chl = wv * 4 + c, ch = chbase + chl, h = h0 + chl;
        float QrA[4], QiA[4], QrB[4], QiB[4];
        {
            const float* qb = Qt + (size_t)h * 64;
            #pragma unroll
            for (int r = 0; r < 4; ++r) {
                QrA[r] = qb[lo + r];      QrB[r] = qb[16 + lo + r];
                QiA[r] = qb[32 + lo + r]; QiB[r] = qb[48 + lo + r];
            }
        }

        #define PSTEP(CTRL) { \
            float Y0[4], Y1[4], Y2[4], Y3[4]; \
            _Pragma("unroll") for (int r = 0; r < 4; ++r) { \
                Y0[r] = dpp_shr<CTRL>(acc_s[c][0][r]); Y1[r] = dpp_shr<CTRL>(acc_s[c][1][r]); \
                Y2[r] = dpp_shr<CTRL>(acc_s[c][2][r]); Y3[r] = dpp_shr<CTRL>(acc_s[c][3][r]); } \
            _Pragma("unroll") for (int r = 0; r < 4; ++r) { \
                acc_s[c][0][r] += QrA[r]*Y0[r] - QiA[r]*Y2[r]; \
                acc_s[c][2][r] += QrA[r]*Y2[r] + QiA[r]*Y0[r]; \
                acc_s[c][1][r] += QrB[r]*Y1[r] - QiB[r]*Y3[r]; \
                acc_s[c][3][r] += QrB[r]*Y3[r] + QiB[r]*Y1[r]; } }
        #define QSQ { _Pragma("unroll") for (int r = 0; r < 4; ++r) { \
            float tA = QrA[r]*QrA[r] - QiA[r]*QiA[r]; QiA[r] = 2.f*QrA[r]*QiA[r]; QrA[r] = tA; \
            float tB = QrB[r]*QrB[r] - QiB[r]*QiB[r]; QiB[r] = 2.f*QrB[r]*QiB[r]; QrB[r] = tB; } }
        PSTEP(0x111) QSQ
        PSTEP(0x112) QSQ
        PSTEP(0x114) QSQ
        PSTEP(0x118)
        #undef PSTEP
        #undef QSQ

        if (cgp == 0) {
            // xbuf slots lr+1 = abs states; slot0 = zeros; publish slot15
            #pragma unroll
            for (int mt = 0; mt < 4; ++mt) {
                *(unsigned*)&xbuf[chl][lr + 1][16*mt + lo]     = cvt_pk_bf16(acc_s[c][mt][0], acc_s[c][mt][1]);
                *(unsigned*)&xbuf[chl][lr + 1][16*mt + lo + 2] = cvt_pk_bf16(acc_s[c][mt][2], acc_s[c][mt][3]);
            }
            if (lr == 0) {
                #pragma unroll
                for (int g2 = 0; g2 < 4; ++g2) {
                    *(unsigned*)&xbuf[chl][0][16*g2 + lo]     = 0u;
                    *(unsigned*)&xbuf[chl][0][16*g2 + lo + 2] = 0u;
                }
            }
            if (lr == 15) {
                float* cb = carry + (size_t)ch * 64;
                #pragma unroll
                for (int r = 0; r < 4; ++r) {
                    cb[lo + r]      = acc_s[c][0][r];
                    cb[16 + lo + r] = acc_s[c][1][r];
                    cb[32 + lo + r] = acc_s[c][2][r];
                    cb[48 + lo + r] = acc_s[c][3][r];
                }
            }
        }
    }

    if (cgp == 0) {
        __syncthreads();   // all waves' carry stores drained
        if (tid == 0) {
            __threadfence();
            __hip_atomic_store(&flags[chb], 1, __ATOMIC_RELEASE,
                               __HIP_MEMORY_SCOPE_AGENT);
        }
    }

    // ---- T x U (independent of xbuf/carry) -> overlaps cg1's wait ----
    f32x4 acc[4][4];
    Frag UBk[4][2];
    #pragma unroll
    for (int c = 0; c < 4; ++c) {
        const int chl = wv * 4 + c;
        UBk[c][0].s = *(const s8v*)(ubuf + chl * CSTR + l * 8);
        UBk[c][1].s = *(const s8v*)(ubuf + chl * CSTR + (64 + l) * 8);
        #pragma unroll
        for (int mt = 0; mt < 4; ++mt) { f32x4 z = {0.f,0.f,0.f,0.f}; acc[c][mt] = z; }
        #pragma unroll
        for (int ks = 0; ks < 2; ++ks) {
            #pragma unroll
            for (int mt = 0; mt < 4; ++mt) {
                const int base = 63 - 16 * mt + 32 * ks + lk8 - lr;
                float f[8];
                #pragma unroll
                for (int j = 0; j < 8; ++j) f[j] = kcP[chl][base + j];
                Frag TA;
                #pragma unroll
                for (int q = 0; q < 4; ++q) TA.u[q] = cvt_pk_bf16(f[2*q], f[2*q+1]);
                acc[c][mt] = __builtin_amdgcn_mfma_f32_16x16x32_bf16(
                    TA.s, UBk[c][ks].s, acc[c][mt], 0, 0, 0);
            }
        }
    }

    // ---- cg1: wait for carry (should have arrived), correct, write xbuf ----
    if (cgp == 1) {
        if (tid == 0)
            while (__hip_atomic_load(&flags[chb], __ATOMIC_ACQUIRE,
                                     __HIP_MEMORY_SCOPE_AGENT) == 0)
                __builtin_amdgcn_s_sleep(2);
        __syncthreads();

        #pragma unroll
        for (int c = 0; c < 4; ++c) {
            const int chl = wv * 4 + c, ch = chbase + chl, h = h0 + chl;
            // P = Q64^(lr+1), branchless binary powering (e = lr+1 in [1,16])
            float PrA[4], PiA[4], PrB[4], PiB[4];
            {
                const float* qb = Qt + (size_t)h * 64;
                float QrA[4], QiA[4], QrB[4], QiB[4];
                #pragma unroll
                for (int r = 0; r < 4; ++r) {
                    QrA[r] = qb[lo + r];      QrB[r] = qb[16 + lo + r];
                    QiA[r] = qb[32 + lo + r]; QiB[r] = qb[48 + lo + r];
                    PrA[r] = 1.f; PiA[r] = 0.f; PrB[r] = 1.f; PiB[r] = 0.f;
                }
                const int e = lr + 1;
                #pragma unroll
                for (int bit = 0; bit < 5; ++bit) {
                    const bool on = (e >> bit) & 1;
                    #pragma unroll
                    for (int r = 0; r < 4; ++r) {
                        const float nAr = PrA[r]*QrA[r] - PiA[r]*QiA[r];
                        const float nAi = PrA[r]*QiA[r] + PiA[r]*QrA[r];
                        const float nBr = PrB[r]*QrB[r] - PiB[r]*QiB[r];
                        const float nBi = PrB[r]*QiB[r] + PiB[r]*QrB[r];
                        PrA[r] = on ? nAr : PrA[r]; PiA[r] = on ? nAi : PiA[r];
                        PrB[r] = on ? nBr : PrB[r]; PiB[r] = on ? nBi : PiB[r];
                        const float sAr = QrA[r]*QrA[r] - QiA[r]*QiA[r];
                        QiA[r] = 2.f*QrA[r]*QiA[r]; QrA[r] = sAr;
                        const float sBr = QrB[r]*QrB[r] - QiB[r]*QiB[r];
                        QiB[r] = 2.f*QrB[r]*QiB[r]; QrB[r] = sBr;
                    }
                }
            }
            // load C and apply correction abs = prefix_noC + P*C
            const float* cb = carry + (size_t)ch * 64;
            float CrA[4], CiA[4], CrB[4], CiB[4];
            #pragma unroll
            for (int r = 0; r < 4; ++r) {
                CrA[r] = cb[lo + r];      CrB[r] = cb[16 + lo + r];
                CiA[r] = cb[32 + lo + r]; CiB[r] = cb[48 + lo + r];
            }
            #pragma unroll
            for (int r = 0; r < 4; ++r) {
                acc_s[c][0][r] += PrA[r]*CrA[r] - PiA[r]*CiA[r];
                acc_s[c][2][r] += PrA[r]*CiA[r] + PiA[r]*CrA[r];
                acc_s[c][1][r] += PrB[r]*CrB[r] - PiB[r]*CiB[r];
                acc_s[c][3][r] += PrB[r]*CiB[r] + PiB[r]*CrB[r];
            }
            // xbuf slots lr+1 = corrected abs states; slot0 = C
            #pragma unroll
            for (int mt = 0; mt < 4; ++mt) {
                *(unsigned*)&xbuf[chl][lr + 1][16*mt + lo]     = cvt_pk_bf16(acc_s[c][mt][0], acc_s[c][mt][1]);
                *(unsigned*)&xbuf[chl][lr + 1][16*mt + lo + 2] = cvt_pk_bf16(acc_s[c][mt][2], acc_s[c][mt][3]);
            }
            if (lr == 0) {
                *(unsigned*)&xbuf[chl][0][lo]          = cvt_pk_bf16(CrA[0], CrA[1]);
                *(unsigned*)&xbuf[chl][0][lo + 2]      = cvt_pk_bf16(CrA[2], CrA[3]);
                *(unsigned*)&xbuf[chl][0][16 + lo]     = cvt_pk_bf16(CrB[0], CrB[1]);
                *(unsigned*)&xbuf[chl][0][16 + lo + 2] = cvt_pk_bf16(CrB[2], CrB[3]);
                *(unsigned*)&xbuf[chl][0][32 + lo]     = cvt_pk_bf16(CiA[0], CiA[1]);
                *(unsigned*)&xbuf[chl][0][32 + lo + 2] = cvt_pk_bf16(CiA[2], CiA[3]);
                *(unsigned*)&xbuf[chl][0][48 + lo]     = cvt_pk_bf16(CiB[0], CiB[1]);
                *(unsigned*)&xbuf[chl][0][48 + lo + 2] = cvt_pk_bf16(CiB[2], CiB[3]);
            }
        }
    }

    __syncthreads();   // xbuf visible to all waves

    // ---- M x X ----
    #pragma unroll
    for (int c = 0; c < 4; ++c) {
        const int chl = wv * 4 + c, h = h0 + chl;
        Frag XB[2];
        XB[0].s = *(const s8v*)&xbuf[chl][lr][lk8];
        XB[1].s = *(const s8v*)&xbuf[chl][lr][32 + lk8];
        const unsigned short* Mh = Mt + (size_t)h * 4096;
        #pragma unroll
        for (int ks = 0; ks < 2; ++ks) {
            #pragma unroll
            for (int mt = 0; mt < 4; ++mt) {
                Frag MA; MA.s = *(const s8v*)(Mh + (16 * mt + lr) * 64 + ks * 32 + lk8);
                acc[c][mt] = __builtin_amdgcn_mfma_f32_16x16x32_bf16(
                    MA.s, XB[ks].s, acc[c][mt], 0, 0, 0);
            }
        }
    }

    // two-half flush through the swizzled [512][32] y tile (R18/R23 verbatim)
    float* ob = out + ((size_t)b * SEQLEN + cgp * TPG) * HIDDEN + h0;
    #pragma unroll
    for (int half = 0; half < 2; ++half) {
        __syncthreads();
        if ((lr >> 3) == half) {
            const int lr7 = lr & 7;
            #pragma unroll
            for (int c = 0; c < 4; ++c) {
                const int chl = wv * 4 + c;
                const int col = chl ^ (lr7 << 1);
                #pragma unroll
                for (int mt = 0; mt < 4; ++mt)
                    #pragma unroll
                    for (int r = 0; r < 4; ++r) {
                        const int t_loc = lr7 * 64 + 16 * mt + lo + r;
                        ubuf[t_loc * 32 + col] = bf16of(acc[c][mt][r]);
                    }
            }
        }
        __syncthreads();
        float* obh = ob + (size_t)half * 512 * HIDDEN;
        #pragma unroll
        for (int q = 0; q < 8; ++q) {
            const int idx = q * 256 + tid;
            const int t_loc = idx >> 2, a = idx & 3;
            const int lrt = (t_loc >> 6) & 7;
            const int blk = (a ^ (lrt >> 1)) * 4;
            const uint2 w = *(const uint2*)(ubuf + t_loc * 32 + blk);
            const float s0 = bf2f(w.x & 0xffffu), s1 = bf2f(w.x >> 16);
            const float s2 = bf2f(w.y & 0xffffu), s3 = bf2f(w.y >> 16);
            float4 o;
            if (lrt & 1) o = make_float4(s2, s3, s0, s1);
            else         o = make_float4(s0, s1, s2, s3);
            *(float4*)(obh + (size_t)t_loc * HIDDEN + a * 4) = o;
        }
    }
}

extern "C" void kernel_launch(void* const* d_in, const int* in_sizes, int n_in,
                              void* d_out, int out_size, void* d_ws, size_t ws_size,
                              hipStream_t stream) {
    const float* input  = (const float*)d_in[0];
    const float* log_dt = (const float*)d_in[1];
    const float* Dp     = (const float*)d_in[2];
    const float* A_log  = (const float*)d_in[3];
    const float* A_imag = (const float*)d_in[4];
    const float* Bp     = (const float*)d_in[5];
    const float* Cp     = (const float*)d_in[6];
    float* out = (float*)d_out;

    unsigned short* Vt  = (unsigned short*)d_ws;
    unsigned short* Mtb = (unsigned short*)((char*)d_ws + OFF_M);
    float*          kct = (float*)((char*)d_ws + OFF_K);
    float*          Qt  = (float*)((char*)d_ws + OFF_Q);
    float*          carry = (float*)((char*)d_ws + OFF_C);
    int*            flags = (int*)((char*)d_ws + OFF_F);

    hipMemsetAsync(flags, 0, 256 * sizeof(int), stream);
    ssm_tables<<<dim3(1024 * 8), dim3(256), 0, stream>>>(
        log_dt, Dp, A_log, A_imag, Bp, Cp, Vt, Mtb, kct, Qt);
    ssm_fused<<<dim3(512), dim3(256), 0, stream>>>(
        input, Vt, Mtb, kct, Qt, carry, flags, out);
}

// Round 25
// 71.312 us; speedup vs baseline: 1.1637x; 1.1637x over previous
//
#include <hip/hip_runtime.h>
#include <math.h>

#define SEQLEN   2048
#define HIDDEN   1024
#define NMODES   32
#define CHANNELS 4096
#define CHB      16      // channels per block
#define TPG      1024    // timesteps per chunk-group (16 chunks x 64)
#define XP       72      // xbuf inner stride (bf16), 144B rows: 16B-aligned
#define CSTR     1032    // ubuf channel stride in shorts (+16B de-conflict)

typedef float  f2    __attribute__((ext_vector_type(2)));
typedef short  s8v   __attribute__((ext_vector_type(8)));
typedef float  f32x4 __attribute__((ext_vector_type(4)));
union Frag { s8v s; unsigned u[4]; };

// ---- ws layout (bytes) ---------------------------------------------------
#define SZ_V  (1024*64*64*2)              // V table bf16, 8 MiB
#define SZ_M  (1024*64*64*2)              // M table bf16, 8 MiB
#define SZ_K  (1024*64*4)                 // kc f32, 256 KiB
#define SZ_Q  (1024*64*4)                 // A^64 f32, 256 KiB
#define OFF_M (SZ_V)
#define OFF_K (OFF_M + SZ_M)
#define OFF_Q (OFF_K + SZ_K)
#define OFF_C (OFF_Q + SZ_Q)              // carry f32 [ch][64], 1 MiB
#define SZ_C  (CHANNELS*64*4)
#define OFF_F (OFF_C + SZ_C)              // flags int[256]

// ---- helpers -------------------------------------------------------------
template <int CTRL>
__device__ __forceinline__ float dpp_add(float p) {
    int t = __builtin_amdgcn_update_dpp(0, __float_as_int(p), CTRL, 0xF, 0xF, true);
    return p + __int_as_float(t);
}
template <int CTRL>
__device__ __forceinline__ float dpp_shr(float x) {   // lane i <- lane i-s (0 fill)
    int t = __builtin_amdgcn_update_dpp(0, __float_as_int(x), CTRL, 0xF, 0xF, true);
    return __int_as_float(t);
}
__device__ __forceinline__ float sum32_to16(float p) {
    p = dpp_add<0xB1>(p); p = dpp_add<0x4E>(p);
    p = dpp_add<0x124>(p); p = dpp_add<0x128>(p);
    p = dpp_add<0x142>(p);
    return p;
}
__device__ __forceinline__ unsigned cvt_pk_bf16(float lo, float hi) {
    unsigned d; asm("v_cvt_pk_bf16_f32 %0, %1, %2" : "=v"(d) : "v"(lo), "v"(hi)); return d;
}
__device__ __forceinline__ unsigned short bf16of(float x) {
    return (unsigned short)(cvt_pk_bf16(x, x) & 0xffffu);
}
__device__ __forceinline__ float bf2f(unsigned s) {
    return __uint_as_float(s << 16);
}

__device__ __forceinline__ void coef1(
    const float* __restrict__ log_dt, const float* __restrict__ A_log,
    const float* __restrict__ A_imag, const float* __restrict__ Bp,
    const float* __restrict__ Cp, int h, int m,
    float& adr, float& adi, float& bpr, float& bpi)
{
    const int idx = h * NMODES + m;
    const float dt = expf(log_dt[h]);
    const float hd = 0.5f * dt;
    const float ar = -expf(A_log[idx]);
    const float ai = A_imag[idx];
    const float dr = 1.f - hd * ar, di = -hd * ai;
    const float inv = 1.f / (dr * dr + di * di);
    const float nr = 1.f + hd * ar, ni = hd * ai;
    adr = (nr * dr + ni * di) * inv;
    adi = (ni * dr - nr * di) * inv;
    const float tbr = dt * Bp[idx * 2], tbi = dt * Bp[idx * 2 + 1];
    const float bdr = (tbr * dr + tbi * di) * inv;
    const float bdi = (tbi * dr - tbr * di) * inv;
    const float cr = 2.f * Cp[idx * 2], ci = 2.f * Cp[idx * 2 + 1];
    bpr = cr * bdr - ci * bdi;
    bpi = cr * bdi + ci * bdr;
}

// ---- Kernel 0: per-h tables + kc + Qt (A^64) — R23 verbatim --------------
__global__ __launch_bounds__(256) void ssm_tables(
    const float* __restrict__ log_dt, const float* __restrict__ Dp,
    const float* __restrict__ A_log, const float* __restrict__ A_imag,
    const float* __restrict__ Bp, const float* __restrict__ Cp,
    unsigned short* __restrict__ Vt, unsigned short* __restrict__ Mt,
    float* __restrict__ kct, float* __restrict__ Qt)
{
    const int h = blockIdx.x >> 3, dg = blockIdx.x & 7;
    const int tid = threadIdx.x, wv = tid >> 6, l = tid & 63;
    const int m = l & 31;
    const int d = (dg * 4 + wv) * 2 + (l >> 5);

    float adr, adi, bpr, bpi;
    coef1(log_dt, A_log, A_imag, Bp, Cp, h, m, adr, adi, bpr, bpi);

    float Pr = 1.f, Pi = 0.f, Qr = adr, Qi = adi;
    #pragma unroll
    for (int bit = 0; bit < 6; ++bit) {
        if ((d >> bit) & 1) { float t = Pr*Qr - Pi*Qi; Pi = Pr*Qi + Pi*Qr; Pr = t; }
        float tq = Qr*Qr - Qi*Qi; Qi = 2.f*Qr*Qi; Qr = tq;
    }
    const float wr  = Pr*bpr - Pi*bpi, wi  = Pr*bpi + Pi*bpr;   // A^d B'
    const float apr = Pr*adr - Pi*adi, api = Pr*adi + Pi*adr;   // A^{d+1}

    const size_t hb = (size_t)h * 64;
    Vt[(hb + m)      * 64 + (63 - d)] = bf16of(wr);
    Vt[(hb + 32 + m) * 64 + (63 - d)] = bf16of(wi);
    Mt[(hb + d) * 64 + m]       = bf16of(apr);
    Mt[(hb + d) * 64 + 32 + m]  = bf16of(-api);
    if (d == 63) {                       // A^64 (exact f32) for the prefix
        Qt[hb + m]      = apr;
        Qt[hb + 32 + m] = api;
    }

    float s = sum32_to16(wr);
    if ((l & 31) == 16) kct[hb + d] = s + (d == 0 ? Dp[h] : 0.f);
}

// ---- staging: u tile (1024 t x 16 ch) -> frag-ordered bf16 LDS -----------
__device__ __forceinline__ void stage_frag_u(
    const float* __restrict__ ug, unsigned short* __restrict__ ubuf, int tid)
{
    #pragma unroll
    for (int it = 0; it < 16; ++it) {
        const int t_l = it * 64 + (tid >> 2);
        const int c4  = (tid & 3) * 4;
        const float4 g = *(const float4*)(ug + (size_t)t_l * HIDDEN + c4);
        const int n = t_l >> 6, rr = t_l & 63, ksw = rr >> 5, r5 = rr & 31;
        const int lane = (r5 >> 3) * 16 + n, j = r5 & 7;
        const int base = (ksw * 64 + lane) * 8 + j;
        ubuf[(c4 + 0) * CSTR + base] = bf16of(g.x);
        ubuf[(c4 + 1) * CSTR + base] = bf16of(g.y);
        ubuf[(c4 + 2) * CSTR + base] = bf16of(g.z);
        ubuf[(c4 + 3) * CSTR + base] = bf16of(g.w);
    }
    __syncthreads();
}

// ---- Fused: states -> prefix(noC)->xbuf -> T x U -> [cg1: wait+RMW] -> M x X
// grid = 512: blockIdx 0..255 = cg0, 256..511 = cg1. LDS ~80.9KB, 2 blk/CU.
__global__ __launch_bounds__(256) void ssm_fused(
    const float* __restrict__ input,
    const unsigned short* __restrict__ Vt, const unsigned short* __restrict__ Mt,
    const float* __restrict__ kct, const float* __restrict__ Qt,
    float* __restrict__ carry, int* __restrict__ flags, float* __restrict__ out)
{
    __shared__ __align__(16) unsigned short ubuf[CHB * CSTR];   // u frags; later y tile
    __shared__ float kcP[CHB][128];
    __shared__ __align__(16) unsigned short xbuf[CHB][17][XP];  // abs states bf16

    const int tid = threadIdx.x, wv = tid >> 6, l = tid & 63;
    const int cgp = blockIdx.x >> 8;
    const int chb = blockIdx.x & 255;
    const int chbase = chb * CHB;
    const int b = chbase >> 10, h0 = chbase & (HIDDEN - 1);
    const int lr = l & 15, lk8 = ((l >> 4) & 3) * 8, lo = (l >> 4) * 4;

    #pragma unroll
    for (int q = 0; q < 8; ++q) {
        const int idx = q * 256 + tid, chl = idx >> 7, k = idx & 127;
        kcP[chl][k] = (k < 64) ? kct[(size_t)(h0 + chl) * 64 + (63 - k)] : 0.f;
    }
    stage_frag_u(input + ((size_t)b * SEQLEN + cgp * TPG) * HIDDEN + h0, ubuf, tid);

    // ---- phase 1: V x U -> local chunk-end states ----
    f32x4 acc_s[4][4];
    #pragma unroll
    for (int c = 0; c < 4; ++c) {
        const int chl = wv * 4 + c, h = h0 + chl;
        Frag UB0, UB1;
        UB0.s = *(const s8v*)(ubuf + chl * CSTR + l * 8);
        UB1.s = *(const s8v*)(ubuf + chl * CSTR + (64 + l) * 8);
        #pragma unroll
        for (int mt = 0; mt < 4; ++mt) { f32x4 z = {0.f,0.f,0.f,0.f}; acc_s[c][mt] = z; }
        const unsigned short* Vh = Vt + (size_t)h * 4096;
        #pragma unroll
        for (int mt = 0; mt < 4; ++mt) {
            Frag VA0, VA1;
            VA0.s = *(const s8v*)(Vh + (16 * mt + lr) * 64 + lk8);
            VA1.s = *(const s8v*)(Vh + (16 * mt + lr) * 64 + 32 + lk8);
            acc_s[c][mt] = __builtin_amdgcn_mfma_f32_16x16x32_bf16(VA0.s, UB0.s, acc_s[c][mt], 0, 0, 0);
            acc_s[c][mt] = __builtin_amdgcn_mfma_f32_16x16x32_bf16(VA1.s, UB1.s, acc_s[c][mt], 0, 0, 0);
        }
    }

    // ---- prefix WITHOUT carry (both groups); results -> xbuf (acc_s dies) ----
    #pragma unroll
    for (int c = 0; c < 4; ++c) {
        const int chl = wv * 4 + c, ch = chbase + chl, h = h0 + chl;
        float QrA[4], QiA[4], QrB[4], QiB[4];
        {
            const float* qb = Qt + (size_t)h * 64;
            #pragma unroll
            for (int r = 0; r < 4; ++r) {
                QrA[r] = qb[lo + r];      QrB[r] = qb[16 + lo + r];
                QiA[r] = qb[32 + lo + r]; QiB[r] = qb[48 + lo + r];
            }
        }

        #define PSTEP(CTRL) { \
            float Y0[4], Y1[4], Y2[4], Y3[4]; \
            _Pragma("unroll") for (int r = 0; r < 4; ++r) { \
                Y0[r] = dpp_shr<CTRL>(acc_s[c][0][r]); Y1[r] = dpp_shr<CTRL>(acc_s[c][1][r]); \
                Y2[r] = dpp_shr<CTRL>(acc_s[c][2][r]); Y3[r] = dpp_shr<CTRL>(acc_s[c][3][r]); } \
            _Pragma("unroll") for (int r = 0; r < 4; ++r) { \
                acc_s[c][0][r] += QrA[r]*Y0[r] - QiA[r]*Y2[r]; \
                acc_s[c][2][r] += QrA[r]*Y2[r] + QiA[r]*Y0[r]; \
                acc_s[c][1][r] += QrB[r]*Y1[r] - QiB[r]*Y3[r]; \
                acc_s[c][3][r] += QrB[r]*Y3[r] + QiB[r]*Y1[r]; } }
        #define QSQ { _Pragma("unroll") for (int r = 0; r < 4; ++r) { \
            float tA = QrA[r]*QrA[r] - QiA[r]*QiA[r]; QiA[r] = 2.f*QrA[r]*QiA[r]; QrA[r] = tA; \
            float tB = QrB[r]*QrB[r] - QiB[r]*QiB[r]; QiB[r] = 2.f*QrB[r]*QiB[r]; QrB[r] = tB; } }
        PSTEP(0x111) QSQ
        PSTEP(0x112) QSQ
        PSTEP(0x114) QSQ
        PSTEP(0x118)
        #undef PSTEP
        #undef QSQ

        // xbuf slots lr+1 = noC states (cg0: already absolute); slot0 = zeros
        #pragma unroll
        for (int mt = 0; mt < 4; ++mt) {
            *(unsigned*)&xbuf[chl][lr + 1][16*mt + lo]     = cvt_pk_bf16(acc_s[c][mt][0], acc_s[c][mt][1]);
            *(unsigned*)&xbuf[chl][lr + 1][16*mt + lo + 2] = cvt_pk_bf16(acc_s[c][mt][2], acc_s[c][mt][3]);
        }
        if (lr == 0) {
            #pragma unroll
            for (int g2 = 0; g2 < 4; ++g2) {
                *(unsigned*)&xbuf[chl][0][16*g2 + lo]     = 0u;
                *(unsigned*)&xbuf[chl][0][16*g2 + lo + 2] = 0u;
            }
        }
        if (cgp == 0 && lr == 15) {   // publish carry (f32, exact)
            float* cb = carry + (size_t)ch * 64;
            #pragma unroll
            for (int r = 0; r < 4; ++r) {
                cb[lo + r]      = acc_s[c][0][r];
                cb[16 + lo + r] = acc_s[c][1][r];
                cb[32 + lo + r] = acc_s[c][2][r];
                cb[48 + lo + r] = acc_s[c][3][r];
            }
        }
    }

    if (cgp == 0) {
        __syncthreads();   // all waves' carry stores drained
        if (tid == 0) {
            __threadfence();
            __hip_atomic_store(&flags[chb], 1, __ATOMIC_RELEASE,
                               __HIP_MEMORY_SCOPE_AGENT);
        }
    }

    // ---- T x U (independent of xbuf correction) -> overlaps cg1's wait ----
    f32x4 acc[4][4];
    #pragma unroll
    for (int c = 0; c < 4; ++c) {
        const int chl = wv * 4 + c;
        Frag UB[2];
        UB[0].s = *(const s8v*)(ubuf + chl * CSTR + l * 8);
        UB[1].s = *(const s8v*)(ubuf + chl * CSTR + (64 + l) * 8);
        #pragma unroll
        for (int mt = 0; mt < 4; ++mt) { f32x4 z = {0.f,0.f,0.f,0.f}; acc[c][mt] = z; }
        #pragma unroll
        for (int ks = 0; ks < 2; ++ks) {
            #pragma unroll
            for (int mt = 0; mt < 4; ++mt) {
                const int base = 63 - 16 * mt + 32 * ks + lk8 - lr;
                float f[8];
                #pragma unroll
                for (int j = 0; j < 8; ++j) f[j] = kcP[chl][base + j];
                Frag TA;
                #pragma unroll
                for (int q = 0; q < 4; ++q) TA.u[q] = cvt_pk_bf16(f[2*q], f[2*q+1]);
                acc[c][mt] = __builtin_amdgcn_mfma_f32_16x16x32_bf16(
                    TA.s, UB[ks].s, acc[c][mt], 0, 0, 0);
            }
        }
    }

    // ---- cg1: wait for carry, in-place xbuf correction: row lr += Q64^lr * C
    if (cgp == 1) {
        if (tid == 0)
            while (__hip_atomic_load(&flags[chb], __ATOMIC_ACQUIRE,
                                     __HIP_MEMORY_SCOPE_AGENT) == 0)
                __builtin_amdgcn_s_sleep(2);
        __syncthreads();

        #pragma unroll
        for (int c = 0; c < 4; ++c) {
            const int chl = wv * 4 + c, ch = chbase + chl, h = h0 + chl;
            // P = Q64^lr, branchless 4-bit powering (e = lr in [0,15])
            float PrA[4], PiA[4], PrB[4], PiB[4];
            {
                const float* qb = Qt + (size_t)h * 64;
                float QrA[4], QiA[4], QrB[4], QiB[4];
                #pragma unroll
                for (int r = 0; r < 4; ++r) {
                    QrA[r] = qb[lo + r];      QrB[r] = qb[16 + lo + r];
                    QiA[r] = qb[32 + lo + r]; QiB[r] = qb[48 + lo + r];
                    PrA[r] = 1.f; PiA[r] = 0.f; PrB[r] = 1.f; PiB[r] = 0.f;
                }
                #pragma unroll
                for (int bit = 0; bit < 4; ++bit) {
                    const bool on = (lr >> bit) & 1;
                    #pragma unroll
                    for (int r = 0; r < 4; ++r) {
                        const float nAr = PrA[r]*QrA[r] - PiA[r]*QiA[r];
                        const float nAi = PrA[r]*QiA[r] + PiA[r]*QrA[r];
                        const float nBr = PrB[r]*QrB[r] - PiB[r]*QiB[r];
                        const float nBi = PrB[r]*QiB[r] + PiB[r]*QrB[r];
                        PrA[r] = on ? nAr : PrA[r]; PiA[r] = on ? nAi : PiA[r];
                        PrB[r] = on ? nBr : PrB[r]; PiB[r] = on ? nBi : PiB[r];
                        const float sAr = QrA[r]*QrA[r] - QiA[r]*QiA[r];
                        QiA[r] = 2.f*QrA[r]*QiA[r]; QrA[r] = sAr;
                        const float sBr = QrB[r]*QrB[r] - QiB[r]*QiB[r];
                        QiB[r] = 2.f*QrB[r]*QiB[r]; QrB[r] = sBr;
                    }
                }
            }
            // corr = P * C
            const float* cb = carry + (size_t)ch * 64;
            float aR[4], aI[4], bR[4], bI[4];
            #pragma unroll
            for (int r = 0; r < 4; ++r) {
                const float CrA = cb[lo + r],      CrB = cb[16 + lo + r];
                const float CiA = cb[32 + lo + r], CiB = cb[48 + lo + r];
                aR[r] = PrA[r]*CrA - PiA[r]*CiA;
                aI[r] = PrA[r]*CiA + PiA[r]*CrA;
                bR[r] = PrB[r]*CrB - PiB[r]*CiB;
                bI[r] = PrB[r]*CiB + PiB[r]*CrB;
            }
            // in-place RMW of xbuf row lr (4 segments of 4 shorts)
            const float* segs[4] = { aR, bR, aI, bI };
            #pragma unroll
            for (int g2 = 0; g2 < 4; ++g2) {
                unsigned short* p = &xbuf[chl][lr][16*g2 + lo];
                const unsigned w0 = *(unsigned*)p;
                const unsigned w1 = *(unsigned*)(p + 2);
                const float f0 = bf2f(w0 & 0xffffu) + segs[g2][0];
                const float f1 = bf2f(w0 >> 16)     + segs[g2][1];
                const float f2 = bf2f(w1 & 0xffffu) + segs[g2][2];
                const float f3 = bf2f(w1 >> 16)     + segs[g2][3];
                *(unsigned*)p       = cvt_pk_bf16(f0, f1);
                *(unsigned*)(p + 2) = cvt_pk_bf16(f2, f3);
            }
        }
    }

    __syncthreads();   // xbuf final for all waves

    // ---- M x X ----
    #pragma unroll
    for (int c = 0; c < 4; ++c) {
        const int chl = wv * 4 + c, h = h0 + chl;
        Frag XB[2];
        XB[0].s = *(const s8v*)&xbuf[chl][lr][lk8];
        XB[1].s = *(const s8v*)&xbuf[chl][lr][32 + lk8];
        const unsigned short* Mh = Mt + (size_t)h * 4096;
        #pragma unroll
        for (int ks = 0; ks < 2; ++ks) {
            #pragma unroll
            for (int mt = 0; mt < 4; ++mt) {
                Frag MA; MA.s = *(const s8v*)(Mh + (16 * mt + lr) * 64 + ks * 32 + lk8);
                acc[c][mt] = __builtin_amdgcn_mfma_f32_16x16x32_bf16(
                    MA.s, XB[ks].s, acc[c][mt], 0, 0, 0);
            }
        }
    }

    // two-half flush through the swizzled [512][32] y tile (R18/R23 verbatim)
    float* ob = out + ((size_t)b * SEQLEN + cgp * TPG) * HIDDEN + h0;
    #pragma unroll
    for (int half = 0; half < 2; ++half) {
        __syncthreads();
        if ((lr >> 3) == half) {
            const int lr7 = lr & 7;
            #pragma unroll
            for (int c = 0; c < 4; ++c) {
                const int chl = wv * 4 + c;
                const int col = chl ^ (lr7 << 1);
                #pragma unroll
                for (int mt = 0; mt < 4; ++mt)
                    #pragma unroll
                    for (int r = 0; r < 4; ++r) {
                        const int t_loc = lr7 * 64 + 16 * mt + lo + r;
                        ubuf[t_loc * 32 + col] = bf16of(acc[c][mt][r]);
                    }
            }
        }
        __syncthreads();
        float* obh = ob + (size_t)half * 512 * HIDDEN;
        #pragma unroll
        for (int q = 0; q < 8; ++q) {
            const int idx = q * 256 + tid;
            const int t_loc = idx >> 2, a = idx & 3;
            const int lrt = (t_loc >> 6) & 7;
            const int blk = (a ^ (lrt >> 1)) * 4;
            const uint2 w = *(const uint2*)(ubuf + t_loc * 32 + blk);
            const float s0 = bf2f(w.x & 0xffffu), s1 = bf2f(w.x >> 16);
            const float s2 = bf2f(w.y & 0xffffu), s3 = bf2f(w.y >> 16);
            float4 o;
            if (lrt & 1) o = make_float4(s2, s3, s0, s1);
            else         o = make_float4(s0, s1, s2, s3);
            *(float4*)(obh + (size_t)t_loc * HIDDEN + a * 4) = o;
        }
    }
}

extern "C" void kernel_launch(void* const* d_in, const int* in_sizes, int n_in,
                              void* d_out, int out_size, void* d_ws, size_t ws_size,
                              hipStream_t stream) {
    const float* input  = (const float*)d_in[0];
    const float* log_dt = (const float*)d_in[1];
    const float* Dp     = (const float*)d_in[2];
    const float* A_log  = (const float*)d_in[3];
    const float* A_imag = (const float*)d_in[4];
    const float* Bp     = (const float*)d_in[5];
    const float* Cp     = (const float*)d_in[6];
    float* out = (float*)d_out;

    unsigned short* Vt  = (unsigned short*)d_ws;
    unsigned short* Mtb = (unsigned short*)((char*)d_ws + OFF_M);
    float*          kct = (float*)((char*)d_ws + OFF_K);
    float*          Qt  = (float*)((char*)d_ws + OFF_Q);
    float*          carry = (float*)((char*)d_ws + OFF_C);
    int*            flags = (int*)((char*)d_ws + OFF_F);

    hipMemsetAsync(flags, 0, 256 * sizeof(int), stream);
    ssm_tables<<<dim3(1024 * 8), dim3(256), 0, stream>>>(
        log_dt, Dp, A_log, A_imag, Bp, Cp, Vt, Mtb, kct, Qt);
    ssm_fused<<<dim3(512), dim3(256), 0, stream>>>(
        input, Vt, Mtb, kct, Qt, carry, flags, out);
}

// Round 26
// 65.794 us; speedup vs baseline: 1.2613x; 1.0839x over previous
//
#include <hip/hip_runtime.h>
#include <math.h>

#define SEQLEN   2048
#define HIDDEN   1024
#define NMODES   32
#define CHANNELS 4096
#define CHB      16      // channels per block
#define TPG      1024    // timesteps per chunk-group (16 chunks x 64)
#define XP       72      // xbuf inner stride (bf16), 144B rows: 16B-aligned
#define CSTR     1032    // ubuf channel stride in shorts (+16B de-conflict)

typedef float  f2    __attribute__((ext_vector_type(2)));
typedef short  s8v   __attribute__((ext_vector_type(8)));
typedef float  f32x4 __attribute__((ext_vector_type(4)));
union Frag { s8v s; unsigned u[4]; };

// ---- ws layout (bytes) ---------------------------------------------------
#define SZ_V  (1024*64*64*2)              // V table bf16, 8 MiB
#define SZ_M  (1024*64*64*2)              // M table bf16, 8 MiB
#define SZ_K  (1024*64*4)                 // kc f32, 256 KiB
#define SZ_Q  (1024*64*4)                 // A^64 f32, 256 KiB
#define OFF_M (SZ_V)
#define OFF_K (OFF_M + SZ_M)
#define OFF_Q (OFF_K + SZ_K)
#define OFF_C (OFF_Q + SZ_Q)              // carry f32 [ch][64], 1 MiB
#define SZ_C  (CHANNELS*64*4)
#define OFF_F (OFF_C + SZ_C)              // flags int[256]

// ---- helpers -------------------------------------------------------------
template <int CTRL>
__device__ __forceinline__ float dpp_add(float p) {
    int t = __builtin_amdgcn_update_dpp(0, __float_as_int(p), CTRL, 0xF, 0xF, true);
    return p + __int_as_float(t);
}
template <int CTRL>
__device__ __forceinline__ float dpp_shr(float x) {   // lane i <- lane i-s (0 fill)
    int t = __builtin_amdgcn_update_dpp(0, __float_as_int(x), CTRL, 0xF, 0xF, true);
    return __int_as_float(t);
}
__device__ __forceinline__ float sum32_to16(float p) {
    p = dpp_add<0xB1>(p); p = dpp_add<0x4E>(p);
    p = dpp_add<0x124>(p); p = dpp_add<0x128>(p);
    p = dpp_add<0x142>(p);
    return p;
}
__device__ __forceinline__ unsigned cvt_pk_bf16(float lo, float hi) {
    unsigned d; asm("v_cvt_pk_bf16_f32 %0, %1, %2" : "=v"(d) : "v"(lo), "v"(hi)); return d;
}
__device__ __forceinline__ unsigned short bf16of(float x) {
    return (unsigned short)(cvt_pk_bf16(x, x) & 0xffffu);
}
__device__ __forceinline__ float bf2f(unsigned s) {
    return __uint_as_float(s << 16);
}

__device__ __forceinline__ void coef1(
    const float* __restrict__ log_dt, const float* __restrict__ A_log,
    const float* __restrict__ A_imag, const float* __restrict__ Bp,
    const float* __restrict__ Cp, int h, int m,
    float& adr, float& adi, float& bpr, float& bpi)
{
    const int idx = h * NMODES + m;
    const float dt = expf(log_dt[h]);
    const float hd = 0.5f * dt;
    const float ar = -expf(A_log[idx]);
    const float ai = A_imag[idx];
    const float dr = 1.f - hd * ar, di = -hd * ai;
    const float inv = 1.f / (dr * dr + di * di);
    const float nr = 1.f + hd * ar, ni = hd * ai;
    adr = (nr * dr + ni * di) * inv;
    adi = (ni * dr - nr * di) * inv;
    const float tbr = dt * Bp[idx * 2], tbi = dt * Bp[idx * 2 + 1];
    const float bdr = (tbr * dr + tbi * di) * inv;
    const float bdi = (tbi * dr - tbr * di) * inv;
    const float cr = 2.f * Cp[idx * 2], ci = 2.f * Cp[idx * 2 + 1];
    bpr = cr * bdr - ci * bdi;
    bpi = cr * bdi + ci * bdr;
}

// ---- Kernel 0: per-h tables + kc + Qt (A^64); also resets flags ----------
__global__ __launch_bounds__(256) void ssm_tables(
    const float* __restrict__ log_dt, const float* __restrict__ Dp,
    const float* __restrict__ A_log, const float* __restrict__ A_imag,
    const float* __restrict__ Bp, const float* __restrict__ Cp,
    unsigned short* __restrict__ Vt, unsigned short* __restrict__ Mt,
    float* __restrict__ kct, float* __restrict__ Qt,
    int* __restrict__ flags)
{
    const int h = blockIdx.x >> 3, dg = blockIdx.x & 7;
    const int tid = threadIdx.x, wv = tid >> 6, l = tid & 63;
    const int m = l & 31;
    const int d = (dg * 4 + wv) * 2 + (l >> 5);

    if (blockIdx.x == 0) flags[tid] = 0;   // reset handoff flags each call

    float adr, adi, bpr, bpi;
    coef1(log_dt, A_log, A_imag, Bp, Cp, h, m, adr, adi, bpr, bpi);

    float Pr = 1.f, Pi = 0.f, Qr = adr, Qi = adi;
    #pragma unroll
    for (int bit = 0; bit < 6; ++bit) {
        if ((d >> bit) & 1) { float t = Pr*Qr - Pi*Qi; Pi = Pr*Qi + Pi*Qr; Pr = t; }
        float tq = Qr*Qr - Qi*Qi; Qi = 2.f*Qr*Qi; Qr = tq;
    }
    const float wr  = Pr*bpr - Pi*bpi, wi  = Pr*bpi + Pi*bpr;   // A^d B'
    const float apr = Pr*adr - Pi*adi, api = Pr*adi + Pi*adr;   // A^{d+1}

    const size_t hb = (size_t)h * 64;
    Vt[(hb + m)      * 64 + (63 - d)] = bf16of(wr);
    Vt[(hb + 32 + m) * 64 + (63 - d)] = bf16of(wi);
    Mt[(hb + d) * 64 + m]       = bf16of(apr);
    Mt[(hb + d) * 64 + 32 + m]  = bf16of(-api);
    if (d == 63) {                       // A^64 (exact f32) for the prefix
        Qt[hb + m]      = apr;
        Qt[hb + 32 + m] = api;
    }

    float s = sum32_to16(wr);
    if ((l & 31) == 16) kct[hb + d] = s + (d == 0 ? Dp[h] : 0.f);
}

// ---- staging: u tile (1024 t x 16 ch) -> frag-ordered bf16 LDS -----------
__device__ __forceinline__ void stage_frag_u(
    const float* __restrict__ ug, unsigned short* __restrict__ ubuf, int tid)
{
    #pragma unroll
    for (int it = 0; it < 16; ++it) {
        const int t_l = it * 64 + (tid >> 2);
        const int c4  = (tid & 3) * 4;
        const float4 g = *(const float4*)(ug + (size_t)t_l * HIDDEN + c4);
        const int n = t_l >> 6, rr = t_l & 63, ksw = rr >> 5, r5 = rr & 31;
        const int lane = (r5 >> 3) * 16 + n, j = r5 & 7;
        const int base = (ksw * 64 + lane) * 8 + j;
        ubuf[(c4 + 0) * CSTR + base] = bf16of(g.x);
        ubuf[(c4 + 1) * CSTR + base] = bf16of(g.y);
        ubuf[(c4 + 2) * CSTR + base] = bf16of(g.z);
        ubuf[(c4 + 3) * CSTR + base] = bf16of(g.w);
    }
    __syncthreads();
}

// ---- Fused: states -> prefix(noC)->xbuf -> T x U -> [cg1: wait+RMW] -> M x X
// grid = 512: blockIdx 0..255 = cg0, 256..511 = cg1. LDS ~80.9KB, 2 blk/CU.
__global__ __launch_bounds__(256) void ssm_fused(
    const float* __restrict__ input,
    const unsigned short* __restrict__ Vt, const unsigned short* __restrict__ Mt,
    const float* __restrict__ kct, const float* __restrict__ Qt,
    float* __restrict__ carry, int* __restrict__ flags, float* __restrict__ out)
{
    __shared__ __align__(16) unsigned short ubuf[CHB * CSTR];   // u frags; later y tile
    __shared__ float kcP[CHB][128];
    __shared__ __align__(16) unsigned short xbuf[CHB][17][XP];  // abs states bf16

    const int tid = threadIdx.x, wv = tid >> 6, l = tid & 63;
    const int cgp = blockIdx.x >> 8;
    const int chb = blockIdx.x & 255;
    const int chbase = chb * CHB;
    const int b = chbase >> 10, h0 = chbase & (HIDDEN - 1);
    const int lr = l & 15, lk8 = ((l >> 4) & 3) * 8, lo = (l >> 4) * 4;

    #pragma unroll
    for (int q = 0; q < 8; ++q) {
        const int idx = q * 256 + tid, chl = idx >> 7, k = idx & 127;
        kcP[chl][k] = (k < 64) ? kct[(size_t)(h0 + chl) * 64 + (63 - k)] : 0.f;
    }
    stage_frag_u(input + ((size_t)b * SEQLEN + cgp * TPG) * HIDDEN + h0, ubuf, tid);

    // ---- phase 1: V x U -> local chunk-end states; UB frags kept in regs ----
    Frag UBr[4][2];
    f32x4 acc_s[4][4];
    #pragma unroll
    for (int c = 0; c < 4; ++c) {
        const int chl = wv * 4 + c, h = h0 + chl;
        UBr[c][0].s = *(const s8v*)(ubuf + chl * CSTR + l * 8);
        UBr[c][1].s = *(const s8v*)(ubuf + chl * CSTR + (64 + l) * 8);
        #pragma unroll
        for (int mt = 0; mt < 4; ++mt) { f32x4 z = {0.f,0.f,0.f,0.f}; acc_s[c][mt] = z; }
        const unsigned short* Vh = Vt + (size_t)h * 4096;
        #pragma unroll
        for (int mt = 0; mt < 4; ++mt) {
            Frag VA0, VA1;
            VA0.s = *(const s8v*)(Vh + (16 * mt + lr) * 64 + lk8);
            VA1.s = *(const s8v*)(Vh + (16 * mt + lr) * 64 + 32 + lk8);
            acc_s[c][mt] = __builtin_amdgcn_mfma_f32_16x16x32_bf16(VA0.s, UBr[c][0].s, acc_s[c][mt], 0, 0, 0);
            acc_s[c][mt] = __builtin_amdgcn_mfma_f32_16x16x32_bf16(VA1.s, UBr[c][1].s, acc_s[c][mt], 0, 0, 0);
        }
    }

    // ---- prefix WITHOUT carry (both groups); results -> xbuf (acc_s dies) ----
    #pragma unroll
    for (int c = 0; c < 4; ++c) {
        const int chl = wv * 4 + c, ch = chbase + chl, h = h0 + chl;
        float QrA[4], QiA[4], QrB[4], QiB[4];
        {
            const float* qb = Qt + (size_t)h * 64;
            #pragma unroll
            for (int r = 0; r < 4; ++r) {
                QrA[r] = qb[lo + r];      QrB[r] = qb[16 + lo + r];
                QiA[r] = qb[32 + lo + r]; QiB[r] = qb[48 + lo + r];
            }
        }

        #define PSTEP(CTRL) { \
            float Y0[4], Y1[4], Y2[4], Y3[4]; \
            _Pragma("unroll") for (int r = 0; r < 4; ++r) { \
                Y0[r] = dpp_shr<CTRL>(acc_s[c][0][r]); Y1[r] = dpp_shr<CTRL>(acc_s[c][1][r]); \
                Y2[r] = dpp_shr<CTRL>(acc_s[c][2][r]); Y3[r] = dpp_shr<CTRL>(acc_s[c][3][r]); } \
            _Pragma("unroll") for (int r = 0; r < 4; ++r) { \
                acc_s[c][0][r] += QrA[r]*Y0[r] - QiA[r]*Y2[r]; \
                acc_s[c][2][r] += QrA[r]*Y2[r] + QiA[r]*Y0[r]; \
                acc_s[c][1][r] += QrB[r]*Y1[r] - QiB[r]*Y3[r]; \
                acc_s[c][3][r] += QrB[r]*Y3[r] + QiB[r]*Y1[r]; } }
        #define QSQ { _Pragma("unroll") for (int r = 0; r < 4; ++r) { \
            float tA = QrA[r]*QrA[r] - QiA[r]*QiA[r]; QiA[r] = 2.f*QrA[r]*QiA[r]; QrA[r] = tA; \
            float tB = QrB[r]*QrB[r] - QiB[r]*QiB[r]; QiB[r] = 2.f*QrB[r]*QiB[r]; QrB[r] = tB; } }
        PSTEP(0x111) QSQ
        PSTEP(0x112) QSQ
        PSTEP(0x114) QSQ
        PSTEP(0x118)
        #undef PSTEP
        #undef QSQ

        // xbuf slots lr+1 = noC states (cg0: already absolute); slot0 = zeros
        #pragma unroll
        for (int mt = 0; mt < 4; ++mt) {
            *(unsigned*)&xbuf[chl][lr + 1][16*mt + lo]     = cvt_pk_bf16(acc_s[c][mt][0], acc_s[c][mt][1]);
            *(unsigned*)&xbuf[chl][lr + 1][16*mt + lo + 2] = cvt_pk_bf16(acc_s[c][mt][2], acc_s[c][mt][3]);
        }
        if (lr == 0) {
            #pragma unroll
            for (int g2 = 0; g2 < 4; ++g2) {
                *(unsigned*)&xbuf[chl][0][16*g2 + lo]     = 0u;
                *(unsigned*)&xbuf[chl][0][16*g2 + lo + 2] = 0u;
            }
        }
        if (cgp == 0 && lr == 15) {   // publish carry (f32, exact)
            float* cb = carry + (size_t)ch * 64;
            #pragma unroll
            for (int r = 0; r < 4; ++r) {
                cb[lo + r]      = acc_s[c][0][r];
                cb[16 + lo + r] = acc_s[c][1][r];
                cb[32 + lo + r] = acc_s[c][2][r];
                cb[48 + lo + r] = acc_s[c][3][r];
            }
        }
    }

    if (cgp == 0) {
        __syncthreads();   // all waves' carry stores drained
        if (tid == 0) {
            __threadfence();
            __hip_atomic_store(&flags[chb], 1, __ATOMIC_RELEASE,
                               __HIP_MEMORY_SCOPE_AGENT);
        }
    }

    // ---- T x U (UB from regs; independent of xbuf) -> overlaps cg1's wait ----
    f32x4 acc[4][4];
    #pragma unroll
    for (int c = 0; c < 4; ++c) {
        const int chl = wv * 4 + c;
        #pragma unroll
        for (int mt = 0; mt < 4; ++mt) { f32x4 z = {0.f,0.f,0.f,0.f}; acc[c][mt] = z; }
        #pragma unroll
        for (int ks = 0; ks < 2; ++ks) {
            #pragma unroll
            for (int mt = 0; mt < 4; ++mt) {
                const int base = 63 - 16 * mt + 32 * ks + lk8 - lr;
                float f[8];
                #pragma unroll
                for (int j = 0; j < 8; ++j) f[j] = kcP[chl][base + j];
                Frag TA;
                #pragma unroll
                for (int q = 0; q < 4; ++q) TA.u[q] = cvt_pk_bf16(f[2*q], f[2*q+1]);
                acc[c][mt] = __builtin_amdgcn_mfma_f32_16x16x32_bf16(
                    TA.s, UBr[c][ks].s, acc[c][mt], 0, 0, 0);
            }
        }
    }

    // ---- cg1: wait for carry, in-place xbuf correction: row lr += Q64^lr * C
    if (cgp == 1) {
        if (tid == 0)
            while (__hip_atomic_load(&flags[chb], __ATOMIC_ACQUIRE,
                                     __HIP_MEMORY_SCOPE_AGENT) == 0)
                __builtin_amdgcn_s_sleep(2);
        __syncthreads();

        #pragma unroll
        for (int c = 0; c < 4; ++c) {
            const int chl = wv * 4 + c, ch = chbase + chl, h = h0 + chl;
            // P = Q64^lr, branchless 4-bit powering (e = lr in [0,15])
            float PrA[4], PiA[4], PrB[4], PiB[4];
            {
                const float* qb = Qt + (size_t)h * 64;
                float QrA[4], QiA[4], QrB[4], QiB[4];
                #pragma unroll
                for (int r = 0; r < 4; ++r) {
                    QrA[r] = qb[lo + r];      QrB[r] = qb[16 + lo + r];
                    QiA[r] = qb[32 + lo + r]; QiB[r] = qb[48 + lo + r];
                    PrA[r] = 1.f; PiA[r] = 0.f; PrB[r] = 1.f; PiB[r] = 0.f;
                }
                #pragma unroll
                for (int bit = 0; bit < 4; ++bit) {
                    const bool on = (lr >> bit) & 1;
                    #pragma unroll
                    for (int r = 0; r < 4; ++r) {
                        const float nAr = PrA[r]*QrA[r] - PiA[r]*QiA[r];
                        const float nAi = PrA[r]*QiA[r] + PiA[r]*QrA[r];
                        const float nBr = PrB[r]*QrB[r] - PiB[r]*QiB[r];
                        const float nBi = PrB[r]*QiB[r] + PiB[r]*QrB[r];
                        PrA[r] = on ? nAr : PrA[r]; PiA[r] = on ? nAi : PiA[r];
                        PrB[r] = on ? nBr : PrB[r]; PiB[r] = on ? nBi : PiB[r];
                        const float sAr = QrA[r]*QrA[r] - QiA[r]*QiA[r];
                        QiA[r] = 2.f*QrA[r]*QiA[r]; QrA[r] = sAr;
                        const float sBr = QrB[r]*QrB[r] - QiB[r]*QiB[r];
                        QiB[r] = 2.f*QrB[r]*QiB[r]; QrB[r] = sBr;
                    }
                }
            }
            // corr = P * C
            const float* cb = carry + (size_t)ch * 64;
            float aR[4], aI[4], bR[4], bI[4];
            #pragma unroll
            for (int r = 0; r < 4; ++r) {
                const float CrA = cb[lo + r],      CrB = cb[16 + lo + r];
                const float CiA = cb[32 + lo + r], CiB = cb[48 + lo + r];
                aR[r] = PrA[r]*CrA - PiA[r]*CiA;
                aI[r] = PrA[r]*CiA + PiA[r]*CrA;
                bR[r] = PrB[r]*CrB - PiB[r]*CiB;
                bI[r] = PrB[r]*CiB + PiB[r]*CrB;
            }
            // in-place RMW of xbuf row lr (4 segments of 4 shorts)
            const float* segs[4] = { aR, bR, aI, bI };
            #pragma unroll
            for (int g2 = 0; g2 < 4; ++g2) {
                unsigned short* p = &xbuf[chl][lr][16*g2 + lo];
                const unsigned w0 = *(unsigned*)p;
                const unsigned w1 = *(unsigned*)(p + 2);
                const float f0 = bf2f(w0 & 0xffffu) + segs[g2][0];
                const float f1 = bf2f(w0 >> 16)     + segs[g2][1];
                const float f2 = bf2f(w1 & 0xffffu) + segs[g2][2];
                const float f3 = bf2f(w1 >> 16)     + segs[g2][3];
                *(unsigned*)p       = cvt_pk_bf16(f0, f1);
                *(unsigned*)(p + 2) = cvt_pk_bf16(f2, f3);
            }
        }
    }

    __syncthreads();   // xbuf final for all waves

    // ---- M x X ----
    #pragma unroll
    for (int c = 0; c < 4; ++c) {
        const int chl = wv * 4 + c, h = h0 + chl;
        Frag XB[2];
        XB[0].s = *(const s8v*)&xbuf[chl][lr][lk8];
        XB[1].s = *(const s8v*)&xbuf[chl][lr][32 + lk8];
        const unsigned short* Mh = Mt + (size_t)h * 4096;
        #pragma unroll
        for (int ks = 0; ks < 2; ++ks) {
            #pragma unroll
            for (int mt = 0; mt < 4; ++mt) {
                Frag MA; MA.s = *(const s8v*)(Mh + (16 * mt + lr) * 64 + ks * 32 + lk8);
                acc[c][mt] = __builtin_amdgcn_mfma_f32_16x16x32_bf16(
                    MA.s, XB[ks].s, acc[c][mt], 0, 0, 0);
            }
        }
    }

    // two-half flush through the swizzled [512][32] y tile (R18/R23 verbatim)
    float* ob = out + ((size_t)b * SEQLEN + cgp * TPG) * HIDDEN + h0;
    #pragma unroll
    for (int half = 0; half < 2; ++half) {
        __syncthreads();
        if ((lr >> 3) == half) {
            const int lr7 = lr & 7;
            #pragma unroll
            for (int c = 0; c < 4; ++c) {
                const int chl = wv * 4 + c;
                const int col = chl ^ (lr7 << 1);
                #pragma unroll
                for (int mt = 0; mt < 4; ++mt)
                    #pragma unroll
                    for (int r = 0; r < 4; ++r) {
                        const int t_loc = lr7 * 64 + 16 * mt + lo + r;
                        ubuf[t_loc * 32 + col] = bf16of(acc[c][mt][r]);
                    }
            }
        }
        __syncthreads();
        float* obh = ob + (size_t)half * 512 * HIDDEN;
        #pragma unroll
        for (int q = 0; q < 8; ++q) {
            const int idx = q * 256 + tid;
            const int t_loc = idx >> 2, a = idx & 3;
            const int lrt = (t_loc >> 6) & 7;
            const int blk = (a ^ (lrt >> 1)) * 4;
            const uint2 w = *(const uint2*)(ubuf + t_loc * 32 + blk);
            const float s0 = bf2f(w.x & 0xffffu), s1 = bf2f(w.x >> 16);
            const float s2 = bf2f(w.y & 0xffffu), s3 = bf2f(w.y >> 16);
            float4 o;
            if (lrt & 1) o = make_float4(s2, s3, s0, s1);
            else         o = make_float4(s0, s1, s2, s3);
            *(float4*)(obh + (size_t)t_loc * HIDDEN + a * 4) = o;
        }
    }
}

extern "C" void kernel_launch(void* const* d_in, const int* in_sizes, int n_in,
                              void* d_out, int out_size, void* d_ws, size_t ws_size,
                              hipStream_t stream) {
    const float* input  = (const float*)d_in[0];
    const float* log_dt = (const float*)d_in[1];
    const float* Dp     = (const float*)d_in[2];
    const float* A_log  = (const float*)d_in[3];
    const float* A_imag = (const float*)d_in[4];
    const float* Bp     = (const float*)d_in[5];
    const float* Cp     = (const float*)d_in[6];
    float* out = (float*)d_out;

    unsigned short* Vt  = (unsigned short*)d_ws;
    unsigned short* Mtb = (unsigned short*)((char*)d_ws + OFF_M);
    float*          kct = (float*)((char*)d_ws + OFF_K);
    float*          Qt  = (float*)((char*)d_ws + OFF_Q);
    float*          carry = (float*)((char*)d_ws + OFF_C);
    int*            flags = (int*)((char*)d_ws + OFF_F);

    ssm_tables<<<dim3(1024 * 8), dim3(256), 0, stream>>>(
        log_dt, Dp, A_log, A_imag, Bp, Cp, Vt, Mtb, kct, Qt, flags);
    ssm_fused<<<dim3(512), dim3(256), 0, stream>>>(
        input, Vt, Mtb, kct, Qt, carry, flags, out);
}